// Round 16
// baseline (596.124 us; speedup 1.0000x reference)
//
#include <hip/hip_runtime.h>

#define NROWS 32768   // B*T = 16*2048
#define DIM 256
#define KCODES 1024
#define NLEV 4
#define CAP 64
#define MARGIN 8e-3f

typedef short short8v __attribute__((ext_vector_type(8)));
typedef float f32x4v  __attribute__((ext_vector_type(4)));

// bf16 round-to-nearest-even
static __device__ __forceinline__ unsigned short f2bf(float f) {
  unsigned u = __float_as_uint(f);
  unsigned lsb = (u >> 16) & 1u;
  u += 0x7fffu + lsb;
  return (unsigned short)(u >> 16);
}

// Packed fragment layout (per 16-row/16-code tile of 256 dims = 4096 shorts):
//   pak[tile][ks*512 + kb*128 + r8*8 + j] = elem(row = tile*16 + r8,
//                                               k = ks*32 + kb*8 + j)
// Wave reads short8v at pak + tile*4096 + ks*512 + lane*8 -> contiguous 1 KB.

// ============ codebook squared norms (unchanged, verified) ============
__global__ __launch_bounds__(256) void k_bnorm(const float* __restrict__ cb,
                                               float* __restrict__ bv) {
  int r = blockIdx.x * blockDim.x + threadIdx.x;
  if (r >= NLEV * KCODES) return;
  const float4* p = reinterpret_cast<const float4*>(cb + (size_t)r * DIM);
  float s0 = 0.f, s1 = 0.f, s2 = 0.f, s3 = 0.f;
  for (int g = 0; g < DIM / 4; ++g) {
    float4 v = p[g];
    s0 += v.x * v.x; s1 += v.y * v.y; s2 += v.z * v.z; s3 += v.w * v.w;
  }
  bv[r] = (s0 + s1) + (s2 + s3);
}

// ============ codebook -> bf16, PACKED fragment layout (verified r15) ============
__global__ __launch_bounds__(256) void k_csplit(const float* __restrict__ cb,
                                                unsigned short* __restrict__ chi) {
  const int tid = threadIdx.x;
  const int cr = blockIdx.x * 16 + (tid >> 4);
  const int l16 = tid & 15;
  const float4* p = reinterpret_cast<const float4*>(cb + (size_t)cr * DIM + l16 * 16);
  unsigned w[8];
  #pragma unroll
  for (int j = 0; j < 4; ++j) {
    float4 v = p[j];
    w[2 * j + 0] = (unsigned)f2bf(v.x) | ((unsigned)f2bf(v.y) << 16);
    w[2 * j + 1] = (unsigned)f2bf(v.z) | ((unsigned)f2bf(v.w) << 16);
  }
  const int lvl_ = cr >> 10;
  const int c = cr & 1023;
  unsigned short* base = chi + (size_t)lvl_ * (KCODES * DIM) + (size_t)(c >> 4) * 4096;
  const int c8 = c & 15;
  const int ks = l16 >> 1;
  const int kb0 = (l16 & 1) * 2;
  *reinterpret_cast<uint4*>(base + ks * 512 + kb0 * 128 + c8 * 8) =
      make_uint4(w[0], w[1], w[2], w[3]);
  *reinterpret_cast<uint4*>(base + ks * 512 + (kb0 + 1) * 128 + c8 * 8) =
      make_uint4(w[4], w[5], w[6], w[7]);
}

// ============ x -> rowsq + rhi (PACKED, verified r15) ============
__global__ __launch_bounds__(256) void k_prep(const float* __restrict__ x,
                                              unsigned short* __restrict__ rhi,
                                              float* __restrict__ rowsq) {
  __shared__ float sred[256];
  const int tid = threadIdx.x;
  const int rr = tid >> 4;
  const int l16 = tid & 15;
  const int row = blockIdx.x * 16 + rr;
  const float4* p = reinterpret_cast<const float4*>(x + (size_t)row * DIM + l16 * 16);
  float e = 0.f;
  unsigned w[8];
  #pragma unroll
  for (int j = 0; j < 4; ++j) {
    float4 v = p[j];
    e += v.x * v.x + v.y * v.y + v.z * v.z + v.w * v.w;
    w[2 * j + 0] = (unsigned)f2bf(v.x) | ((unsigned)f2bf(v.y) << 16);
    w[2 * j + 1] = (unsigned)f2bf(v.z) | ((unsigned)f2bf(v.w) << 16);
  }
  unsigned short* base = rhi + (size_t)blockIdx.x * 4096;
  const int ks = l16 >> 1;
  const int kb0 = (l16 & 1) * 2;
  *reinterpret_cast<uint4*>(base + ks * 512 + kb0 * 128 + rr * 8) =
      make_uint4(w[0], w[1], w[2], w[3]);
  *reinterpret_cast<uint4*>(base + ks * 512 + (kb0 + 1) * 128 + rr * 8) =
      make_uint4(w[4], w[5], w[6], w[7]);
  sred[tid] = e;
  __syncthreads();
  if (tid < 16) {
    float s = 0.f;
    #pragma unroll
    for (int k = 0; k < 16; ++k) s += sred[tid * 16 + k];
    rowsq[blockIdx.x * 16 + tid] = s;
  }
}

// ============ MFMA bf16 screen, half-panel blocks + prefetch rotation ============
// 1024 blocks = 512 row-tiles (64 rows) x 2 code-halves (512 codes). Wave =
// 2 row-tiles x 8 code-tiles: acc[2][8]=64 AGPR, operand set = 40 VGPR ->
// 2-deep even/odd prefetch keeps a whole ks-set of loads in flight (fixes the
// serialized-latency stall of r15). Survivors vs LOCAL half-min + MARGIN:
// margin 8e-3 >= 2*err(6.4e-3) guarantees the true argmin is emitted by its
// half; other half emits a superset (harmless, u64-min rescore). Slots via
// global atomicAdd on counts (memset per level). Fragments bit-identical.
__global__ __launch_bounds__(512) void k_screen(const unsigned short* __restrict__ rhi,
                                                const unsigned short* __restrict__ chi_l,
                                                const float* __restrict__ bv_l,
                                                const float* __restrict__ rowsq,
                                                unsigned* __restrict__ survq,
                                                unsigned* __restrict__ counts) {
  __shared__ float minb[64][4];
  __shared__ float rowminf[64];
  const int tid = threadIdx.x;
  const int lane = tid & 63;
  const int w = tid >> 6;
  const int rh2 = w >> 2;
  const int cg = w & 3;
  const int rt = blockIdx.x & 511;
  const int half = blockIdx.x >> 9;
  const int row0 = rt * 64 + rh2 * 32;
  const int c0 = half * 512 + cg * 128;
  const int ln = lane & 15;
  const int kb = lane >> 4;

  f32x4v acc[2][8];
  #pragma unroll
  for (int r = 0; r < 2; ++r)
    #pragma unroll
    for (int t = 0; t < 8; ++t) acc[r][t] = (f32x4v){0.f, 0.f, 0.f, 0.f};

  const unsigned short* pa = rhi + (size_t)(rt * 4 + rh2 * 2) * 4096 + lane * 8;
  const unsigned short* pb = chi_l + (size_t)(c0 >> 4) * 4096 + lane * 8;

  short8v a0A, a1A, bA0, bA1, bA2, bA3, bA4, bA5, bA6, bA7;
  short8v a0B, a1B, bB0, bB1, bB2, bB3, bB4, bB5, bB6, bB7;

#define LOADSET(A0, A1, B0, B1, B2, B3, B4, B5, B6, B7, KS)                   \
  A0 = *reinterpret_cast<const short8v*>(pa + (KS) * 512);                    \
  A1 = *reinterpret_cast<const short8v*>(pa + 4096 + (KS) * 512);             \
  B0 = *reinterpret_cast<const short8v*>(pb + 0 * 4096 + (KS) * 512);         \
  B1 = *reinterpret_cast<const short8v*>(pb + 1 * 4096 + (KS) * 512);         \
  B2 = *reinterpret_cast<const short8v*>(pb + 2 * 4096 + (KS) * 512);         \
  B3 = *reinterpret_cast<const short8v*>(pb + 3 * 4096 + (KS) * 512);         \
  B4 = *reinterpret_cast<const short8v*>(pb + 4 * 4096 + (KS) * 512);         \
  B5 = *reinterpret_cast<const short8v*>(pb + 5 * 4096 + (KS) * 512);         \
  B6 = *reinterpret_cast<const short8v*>(pb + 6 * 4096 + (KS) * 512);         \
  B7 = *reinterpret_cast<const short8v*>(pb + 7 * 4096 + (KS) * 512);

#define MFMASET(A0, A1, B0, B1, B2, B3, B4, B5, B6, B7)                       \
  acc[0][0] = __builtin_amdgcn_mfma_f32_16x16x32_bf16(A0, B0, acc[0][0], 0, 0, 0); \
  acc[1][0] = __builtin_amdgcn_mfma_f32_16x16x32_bf16(A1, B0, acc[1][0], 0, 0, 0); \
  acc[0][1] = __builtin_amdgcn_mfma_f32_16x16x32_bf16(A0, B1, acc[0][1], 0, 0, 0); \
  acc[1][1] = __builtin_amdgcn_mfma_f32_16x16x32_bf16(A1, B1, acc[1][1], 0, 0, 0); \
  acc[0][2] = __builtin_amdgcn_mfma_f32_16x16x32_bf16(A0, B2, acc[0][2], 0, 0, 0); \
  acc[1][2] = __builtin_amdgcn_mfma_f32_16x16x32_bf16(A1, B2, acc[1][2], 0, 0, 0); \
  acc[0][3] = __builtin_amdgcn_mfma_f32_16x16x32_bf16(A0, B3, acc[0][3], 0, 0, 0); \
  acc[1][3] = __builtin_amdgcn_mfma_f32_16x16x32_bf16(A1, B3, acc[1][3], 0, 0, 0); \
  acc[0][4] = __builtin_amdgcn_mfma_f32_16x16x32_bf16(A0, B4, acc[0][4], 0, 0, 0); \
  acc[1][4] = __builtin_amdgcn_mfma_f32_16x16x32_bf16(A1, B4, acc[1][4], 0, 0, 0); \
  acc[0][5] = __builtin_amdgcn_mfma_f32_16x16x32_bf16(A0, B5, acc[0][5], 0, 0, 0); \
  acc[1][5] = __builtin_amdgcn_mfma_f32_16x16x32_bf16(A1, B5, acc[1][5], 0, 0, 0); \
  acc[0][6] = __builtin_amdgcn_mfma_f32_16x16x32_bf16(A0, B6, acc[0][6], 0, 0, 0); \
  acc[1][6] = __builtin_amdgcn_mfma_f32_16x16x32_bf16(A1, B6, acc[1][6], 0, 0, 0); \
  acc[0][7] = __builtin_amdgcn_mfma_f32_16x16x32_bf16(A0, B7, acc[0][7], 0, 0, 0); \
  acc[1][7] = __builtin_amdgcn_mfma_f32_16x16x32_bf16(A1, B7, acc[1][7], 0, 0, 0);

  LOADSET(a0A, a1A, bA0, bA1, bA2, bA3, bA4, bA5, bA6, bA7, 0)
  #pragma unroll 1
  for (int i = 0; i < 4; ++i) {
    LOADSET(a0B, a1B, bB0, bB1, bB2, bB3, bB4, bB5, bB6, bB7, 2 * i + 1)
    MFMASET(a0A, a1A, bA0, bA1, bA2, bA3, bA4, bA5, bA6, bA7)
    if (i < 3) {
      LOADSET(a0A, a1A, bA0, bA1, bA2, bA3, bA4, bA5, bA6, bA7, 2 * i + 2)
    }
    MFMASET(a0B, a1B, bB0, bB1, bB2, bB3, bB4, bB5, bB6, bB7)
  }
#undef LOADSET
#undef MFMASET

  float bvl[8];
  #pragma unroll
  for (int t = 0; t < 8; ++t) bvl[t] = bv_l[c0 + t * 16 + ln];
  float rq[2][4];
  #pragma unroll
  for (int r = 0; r < 2; ++r)
    #pragma unroll
    for (int g = 0; g < 4; ++g) rq[r][g] = rowsq[row0 + r * 16 + kb * 4 + g];

  #pragma unroll
  for (int r = 0; r < 2; ++r) {
    #pragma unroll
    for (int g = 0; g < 4; ++g) {
      float v = __builtin_inff();
      #pragma unroll
      for (int t = 0; t < 8; ++t) {
        float dd = (rq[r][g] + bvl[t]) - 2.0f * acc[r][t][g];
        v = fminf(v, dd);
      }
      #pragma unroll
      for (int m = 1; m < 16; m <<= 1) v = fminf(v, __shfl_xor(v, m));
      if (ln == 0) minb[rh2 * 32 + r * 16 + kb * 4 + g][cg] = v;
    }
  }
  __syncthreads();
  if (tid < 64) {
    rowminf[tid] = fminf(fminf(minb[tid][0], minb[tid][1]),
                         fminf(minb[tid][2], minb[tid][3]));
  }
  __syncthreads();
  #pragma unroll
  for (int r = 0; r < 2; ++r) {
    #pragma unroll
    for (int g = 0; g < 4; ++g) {
      const int rowloc = rh2 * 32 + r * 16 + kb * 4 + g;
      const int rowg = rt * 64 + rowloc;
      const float thr = rowminf[rowloc] + MARGIN;
      #pragma unroll
      for (int t = 0; t < 8; ++t) {
        float dd = (rq[r][g] + bvl[t]) - 2.0f * acc[r][t][g];
        if (dd <= thr) {
          unsigned slot = atomicAdd(&counts[rowg], 1u);
          if (slot < CAP)
            survq[(size_t)rowg * CAP + slot] = (unsigned)(c0 + t * 16 + ln);
        }
      }
    }
  }
}

// ============ fused exact rescore + residual update (verified r14/r15) ============
__global__ __launch_bounds__(256) void k_exupd(const float* __restrict__ x,
                                               const float* __restrict__ cb,
                                               const float* __restrict__ bv,
                                               const float* __restrict__ rowsq,
                                               const unsigned* __restrict__ survq,
                                               const unsigned* __restrict__ counts,
                                               int* __restrict__ idxh,
                                               float* __restrict__ fidx,
                                               float* __restrict__ tq,
                                               float* __restrict__ part,
                                               float* __restrict__ rowsq_o,
                                               unsigned short* __restrict__ rhi,
                                               int lvl) {
  __shared__ __align__(16) float rlds[16][260];
  __shared__ int idsh[16];
  __shared__ float sred[256];
  __shared__ float rsum[16];

  const int tid = threadIdx.x;
  const int rr = tid >> 4;
  const int l16 = tid & 15;
  const int row = blockIdx.x * 16 + rr;
  const size_t obase = (size_t)row * DIM + l16 * 16;
  const float* cb_l = cb + (size_t)lvl * KCODES * DIM;
  const float* bv_l = bv + lvl * KCODES;

  // ---- phase A: residual via verified fl chain; stage row in LDS ----
  float4 xj[4], rj[4];
  {
    const float4* xp = reinterpret_cast<const float4*>(x + obase);
    #pragma unroll
    for (int j = 0; j < 4; ++j) { xj[j] = xp[j]; rj[j] = xj[j]; }
    for (int p = 0; p < lvl; ++p) {
      const float4* qp = reinterpret_cast<const float4*>(
          cb + ((size_t)p * KCODES + idxh[p * NROWS + row]) * DIM + l16 * 16);
      #pragma unroll
      for (int j = 0; j < 4; ++j) {
        float4 q = qp[j];
        rj[j].x -= q.x; rj[j].y -= q.y; rj[j].z -= q.z; rj[j].w -= q.w;
      }
    }
    #pragma unroll
    for (int j = 0; j < 4; ++j)
      *reinterpret_cast<float4*>(&rlds[rr][l16 * 16 + 4 * j]) = rj[j];
  }
  __syncthreads();

  // ---- phase B: exact chains on survivors ----
  const float A = rowsq[row];
  const unsigned n = counts[row];
  unsigned long long best = ~0ull;

#define CHAIN(CODE)                                                            \
  {                                                                            \
    const float* cp2 = cb_l + (size_t)(CODE) * DIM;                            \
    float a0 = 0.f;                                                            \
    _Pragma("unroll 8")                                                        \
    for (int dv = 0; dv < DIM / 4; ++dv) {                                     \
      float4 rv = *reinterpret_cast<const float4*>(&rlds[rr][dv * 4]);         \
      float4 cv = *reinterpret_cast<const float4*>(cp2 + dv * 4);              \
      a0 = fmaf(rv.x, cv.x, a0); a0 = fmaf(rv.y, cv.y, a0);                    \
      a0 = fmaf(rv.z, cv.z, a0); a0 = fmaf(rv.w, cv.w, a0);                    \
    }                                                                          \
    float t = A + bv_l[(CODE)];   /* fl(A + B) */                              \
    float dd = t - 2.0f * a0;     /* one rounding (2*dot exact) */             \
    unsigned long long pk =                                                    \
        ((unsigned long long)__float_as_uint(dd) << 32) | (unsigned)(CODE);    \
    best = (pk < best) ? pk : best;                                            \
  }

  if (n <= CAP) {
    for (unsigned s = l16; s < n; s += 16) {
      unsigned code = survq[(size_t)row * CAP + s];
      CHAIN(code);
    }
  } else {
    for (unsigned c = l16; c < KCODES; c += 16) CHAIN(c);  // safety net
  }
#undef CHAIN

  #pragma unroll
  for (int m = 1; m < 16; m <<= 1) {
    unsigned long long o = __shfl_xor(best, m);
    best = (o < best) ? o : best;
  }
  if (l16 == 0) {
    const int id = (int)(best & 0xffffffffull);
    idxh[lvl * NROWS + row] = id;
    fidx[lvl * NROWS + row] = (float)id;
    idsh[rr] = id;
  }
  __syncthreads();

  // ---- phase C: verified k_update math inline ----
  const int id = idsh[rr];
  const float4* cpc = reinterpret_cast<const float4*>(
      cb_l + (size_t)id * DIM + l16 * 16);
  float4* tp = reinterpret_cast<float4*>(tq + obase);
  float nn[16];
  float e = 0.f;
  #pragma unroll
  for (int j = 0; j < 4; ++j) {
    float4 c = cpc[j];
    float n0 = rj[j].x - c.x, n1 = rj[j].y - c.y;
    float n2 = rj[j].z - c.z, n3 = rj[j].w - c.w;
    nn[4 * j + 0] = n0; nn[4 * j + 1] = n1; nn[4 * j + 2] = n2; nn[4 * j + 3] = n3;
    e += (n0 * n0 + n1 * n1) + (n2 * n2 + n3 * n3);
    float4 tv;
    if (lvl == 0) {
      tv = c;
    } else {
      tv = tp[j];
      tv.x += c.x; tv.y += c.y; tv.z += c.z; tv.w += c.w;
    }
    if (lvl == 3) {
      tv.x = xj[j].x + (tv.x - xj[j].x); tv.y = xj[j].y + (tv.y - xj[j].y);
      tv.z = xj[j].z + (tv.z - xj[j].z); tv.w = xj[j].w + (tv.w - xj[j].w);
    }
    tp[j] = tv;
  }

  if (lvl < 3) {
    unsigned w[8];
    #pragma unroll
    for (int k = 0; k < 8; ++k)
      w[k] = (unsigned)f2bf(nn[2 * k]) | ((unsigned)f2bf(nn[2 * k + 1]) << 16);
    unsigned short* base = rhi + (size_t)blockIdx.x * 4096;
    const int ks = l16 >> 1;
    const int kb0 = (l16 & 1) * 2;
    *reinterpret_cast<uint4*>(base + ks * 512 + kb0 * 128 + rr * 8) =
        make_uint4(w[0], w[1], w[2], w[3]);
    *reinterpret_cast<uint4*>(base + ks * 512 + (kb0 + 1) * 128 + rr * 8) =
        make_uint4(w[4], w[5], w[6], w[7]);
  }

  sred[tid] = e;
  __syncthreads();
  if (tid < 16) {
    float s = 0.f;
    #pragma unroll
    for (int k = 0; k < 16; ++k) s += sred[tid * 16 + k];
    rsum[tid] = s;
    if (lvl < 3) rowsq_o[blockIdx.x * 16 + tid] = s;
  }
  __syncthreads();
  if (tid == 0) {
    float p = 0.f;
    #pragma unroll
    for (int k = 0; k < 16; ++k) p += rsum[k];
    part[blockIdx.x] = p;
  }
}

// ============ loss finalize (unchanged) ============
__global__ __launch_bounds__(256) void k_loss(const float* __restrict__ part,
                                              float* __restrict__ out) {
  __shared__ float s[256];
  const int tid = threadIdx.x;
  float means[4];
  for (int l = 0; l < 4; ++l) {
    float sum = 0.f;
    for (int i = tid; i < 2048; i += 256) sum += part[l * 2048 + i];
    s[tid] = sum;
    __syncthreads();
    for (int st = 128; st > 0; st >>= 1) {
      if (tid < st) s[tid] += s[tid + st];
      __syncthreads();
    }
    means[l] = s[0] * (1.0f / 8388608.0f);
    __syncthreads();
  }
  if (tid == 0) {
    float t = ((means[0] + means[1]) + means[2]) + means[3];
    float loss = t * 0.25f;
    out[0] = loss;
    out[1] = loss;
  }
}

extern "C" void kernel_launch(void* const* d_in, const int* in_sizes, int n_in,
                              void* d_out, int out_size, void* d_ws, size_t ws_size,
                              hipStream_t stream) {
  const float* x  = (const float*)d_in[0];
  const float* cb = (const float*)d_in[1];
  float* out = (float*)d_out;
  float* ws  = (float*)d_ws;

  // ws layout (float units)
  unsigned short* rhi = (unsigned short*)ws;                         // 4194304 f
  unsigned short* chi = (unsigned short*)(ws + 4194304);             // 524288 f
  unsigned* survq  = (unsigned*)(ws + 4194304 + 524288);             // 2097152 f
  unsigned* counts = (unsigned*)(ws + 4194304 + 524288 + 2097152);   // 32768 f
  int* idxh        = (int*)(ws + 4194304 + 524288 + 2097152 + 32768);  // 131072 f
  float* bv    = ws + 4194304 + 524288 + 2097152 + 32768 + 131072;   // 4096
  float* rowsq = bv + 4096;                                          // 32768
  float* part  = rowsq + 32768;                                      // 8192

  float* tq      = out;                    // total_quant accumulates in d_out
  float* lossout = out + 8388608;
  float* fidx    = out + 8388610;

  k_bnorm<<<16, 256, 0, stream>>>(cb, bv);
  k_csplit<<<256, 256, 0, stream>>>(cb, chi);
  k_prep<<<2048, 256, 0, stream>>>(x, rhi, rowsq);

  for (int l = 0; l < NLEV; ++l) {
    hipMemsetAsync(counts, 0, (size_t)NROWS * sizeof(unsigned), stream);
    k_screen<<<1024, 512, 0, stream>>>(rhi, chi + (size_t)l * KCODES * DIM,
                                       bv + l * KCODES, rowsq, survq, counts);
    k_exupd<<<2048, 256, 0, stream>>>(x, cb, bv, rowsq, survq, counts,
                                      idxh, fidx, tq, part + l * 2048,
                                      rowsq, rhi, l);
  }

  k_loss<<<1, 256, 0, stream>>>(part, lossout);
}

// Round 17
// 584.695 us; speedup vs baseline: 1.0195x; 1.0195x over previous
//
#include <hip/hip_runtime.h>

#define NROWS 32768   // B*T = 16*2048
#define DIM 256
#define KCODES 1024
#define NLEV 4
#define CAP 64
#define MARGIN 8e-3f

typedef short short8v __attribute__((ext_vector_type(8)));
typedef float f32x4v  __attribute__((ext_vector_type(4)));

// bf16 round-to-nearest-even
static __device__ __forceinline__ unsigned short f2bf(float f) {
  unsigned u = __float_as_uint(f);
  unsigned lsb = (u >> 16) & 1u;
  u += 0x7fffu + lsb;
  return (unsigned short)(u >> 16);
}

// Packed fragment layout (per 16-row/16-code tile of 256 dims = 4096 shorts):
//   pak[tile][ks*512 + kb*128 + r8*8 + j] = elem(row = tile*16 + r8,
//                                               k = ks*32 + kb*8 + j)
// Wave reads short8v at pak + tile*4096 + ks*512 + lane*8 -> contiguous 1 KB.

// ============ codebook squared norms (unchanged, verified) ============
__global__ __launch_bounds__(256) void k_bnorm(const float* __restrict__ cb,
                                               float* __restrict__ bv) {
  int r = blockIdx.x * blockDim.x + threadIdx.x;
  if (r >= NLEV * KCODES) return;
  const float4* p = reinterpret_cast<const float4*>(cb + (size_t)r * DIM);
  float s0 = 0.f, s1 = 0.f, s2 = 0.f, s3 = 0.f;
  for (int g = 0; g < DIM / 4; ++g) {
    float4 v = p[g];
    s0 += v.x * v.x; s1 += v.y * v.y; s2 += v.z * v.z; s3 += v.w * v.w;
  }
  bv[r] = (s0 + s1) + (s2 + s3);
}

// ============ codebook -> bf16, PACKED fragment layout (verified r15) ============
__global__ __launch_bounds__(256) void k_csplit(const float* __restrict__ cb,
                                                unsigned short* __restrict__ chi) {
  const int tid = threadIdx.x;
  const int cr = blockIdx.x * 16 + (tid >> 4);
  const int l16 = tid & 15;
  const float4* p = reinterpret_cast<const float4*>(cb + (size_t)cr * DIM + l16 * 16);
  unsigned w[8];
  #pragma unroll
  for (int j = 0; j < 4; ++j) {
    float4 v = p[j];
    w[2 * j + 0] = (unsigned)f2bf(v.x) | ((unsigned)f2bf(v.y) << 16);
    w[2 * j + 1] = (unsigned)f2bf(v.z) | ((unsigned)f2bf(v.w) << 16);
  }
  const int lvl_ = cr >> 10;
  const int c = cr & 1023;
  unsigned short* base = chi + (size_t)lvl_ * (KCODES * DIM) + (size_t)(c >> 4) * 4096;
  const int c8 = c & 15;
  const int ks = l16 >> 1;
  const int kb0 = (l16 & 1) * 2;
  *reinterpret_cast<uint4*>(base + ks * 512 + kb0 * 128 + c8 * 8) =
      make_uint4(w[0], w[1], w[2], w[3]);
  *reinterpret_cast<uint4*>(base + ks * 512 + (kb0 + 1) * 128 + c8 * 8) =
      make_uint4(w[4], w[5], w[6], w[7]);
}

// ============ x -> rowsq + rhi (PACKED, verified r15) ============
__global__ __launch_bounds__(256) void k_prep(const float* __restrict__ x,
                                              unsigned short* __restrict__ rhi,
                                              float* __restrict__ rowsq) {
  __shared__ float sred[256];
  const int tid = threadIdx.x;
  const int rr = tid >> 4;
  const int l16 = tid & 15;
  const int row = blockIdx.x * 16 + rr;
  const float4* p = reinterpret_cast<const float4*>(x + (size_t)row * DIM + l16 * 16);
  float e = 0.f;
  unsigned w[8];
  #pragma unroll
  for (int j = 0; j < 4; ++j) {
    float4 v = p[j];
    e += v.x * v.x + v.y * v.y + v.z * v.z + v.w * v.w;
    w[2 * j + 0] = (unsigned)f2bf(v.x) | ((unsigned)f2bf(v.y) << 16);
    w[2 * j + 1] = (unsigned)f2bf(v.z) | ((unsigned)f2bf(v.w) << 16);
  }
  unsigned short* base = rhi + (size_t)blockIdx.x * 4096;
  const int ks = l16 >> 1;
  const int kb0 = (l16 & 1) * 2;
  *reinterpret_cast<uint4*>(base + ks * 512 + kb0 * 128 + rr * 8) =
      make_uint4(w[0], w[1], w[2], w[3]);
  *reinterpret_cast<uint4*>(base + ks * 512 + (kb0 + 1) * 128 + rr * 8) =
      make_uint4(w[4], w[5], w[6], w[7]);
  sred[tid] = e;
  __syncthreads();
  if (tid < 16) {
    float s = 0.f;
    #pragma unroll
    for (int k = 0; k < 16; ++k) s += sred[tid * 16 + k];
    rowsq[blockIdx.x * 16 + tid] = s;
  }
}

// ============ MFMA bf16 screen, LDS-staged B panel ============
// 512 blocks x 512 thr. Block = 64 rows x 1024 codes (r15 structure: local min
// IS the global min; LDS cnt, no global atomics). Per ks-step the block stages
// the 64 KB B-slice cooperatively into double-buffered LDS (issue loads BEFORE
// compute, ds_write AFTER -> T14 overlap; one barrier/step), waves read
// fragments via conflict-free ds_read_b128 (base + lane*16). A-fragments
// prefetched in regs one step ahead. Fragments bit-identical to r12-r16.
__global__ __launch_bounds__(512) void k_screen(const unsigned short* __restrict__ rhi,
                                                const unsigned short* __restrict__ chi_l,
                                                const float* __restrict__ bv_l,
                                                const float* __restrict__ rowsq,
                                                unsigned* __restrict__ survq,
                                                unsigned* __restrict__ counts) {
  __shared__ __align__(16) unsigned short Blds[2][32768];  // 2 x 64 KB
  __shared__ float minb[64][4];
  __shared__ float rowminf[64];
  __shared__ unsigned cnt[64];
  const int tid = threadIdx.x;
  const int lane = tid & 63;
  const int w = tid >> 6;
  const int rh2 = w >> 2;
  const int cg = w & 3;
  const int row0 = blockIdx.x * 64 + rh2 * 32;
  const int c0 = cg * 256;
  const int ln = lane & 15;
  const int kb = lane >> 4;

  f32x4v acc[2][16];
  #pragma unroll
  for (int r = 0; r < 2; ++r)
    #pragma unroll
    for (int t = 0; t < 16; ++t) acc[r][t] = (f32x4v){0.f, 0.f, 0.f, 0.f};

  const unsigned short* pa = rhi + (size_t)(blockIdx.x * 4 + rh2 * 2) * 4096 + lane * 8;

  // Staging: thread handles chunks c = tid + j*512 (16 B each). Within a wave
  // c>>6 is uniform and c&63 == lane -> global loads are contiguous 1 KB/wave.
  // prologue: stage ks=0 into Blds[0]; prefetch A for ks=0
  {
    #pragma unroll
    for (int j = 0; j < 8; ++j) {
      const int c = tid + j * 512;
      uint4 v = *reinterpret_cast<const uint4*>(
          chi_l + (size_t)(c >> 6) * 4096 + (c & 63) * 8);
      *reinterpret_cast<uint4*>(&Blds[0][c * 8]) = v;
    }
  }
  short8v a0 = *reinterpret_cast<const short8v*>(pa);
  short8v a1 = *reinterpret_cast<const short8v*>(pa + 4096);
  __syncthreads();

  #pragma unroll 1
  for (int ks = 0; ks < 8; ++ks) {
    // issue next slice's global loads now (consumed after compute)
    uint4 st[8];
    short8v a0n, a1n;
    if (ks < 7) {
      #pragma unroll
      for (int j = 0; j < 8; ++j) {
        const int c = tid + j * 512;
        st[j] = *reinterpret_cast<const uint4*>(
            chi_l + (size_t)(c >> 6) * 4096 + (ks + 1) * 512 + (c & 63) * 8);
      }
      a0n = *reinterpret_cast<const short8v*>(pa + (ks + 1) * 512);
      a1n = *reinterpret_cast<const short8v*>(pa + 4096 + (ks + 1) * 512);
    }
    // compute from current buffer
    const unsigned short* bb = &Blds[ks & 1][0];
    #pragma unroll
    for (int t = 0; t < 16; ++t) {
      short8v b = *reinterpret_cast<const short8v*>(
          bb + (cg * 16 + t) * 512 + lane * 8);
      acc[0][t] = __builtin_amdgcn_mfma_f32_16x16x32_bf16(a0, b, acc[0][t], 0, 0, 0);
      acc[1][t] = __builtin_amdgcn_mfma_f32_16x16x32_bf16(a1, b, acc[1][t], 0, 0, 0);
    }
    if (ks < 7) {
      // write-late into the other buffer (safe: all waves finished reading it
      // at the previous step's barrier), then one barrier
      unsigned short* bd = &Blds[(ks + 1) & 1][0];
      #pragma unroll
      for (int j = 0; j < 8; ++j) {
        const int c = tid + j * 512;
        *reinterpret_cast<uint4*>(&bd[c * 8]) = st[j];
      }
      a0 = a0n; a1 = a1n;
      __syncthreads();
    }
  }

  // screen distances + per-row min + survivors (verified r15 logic)
  float bvl[16];
  #pragma unroll
  for (int t = 0; t < 16; ++t) bvl[t] = bv_l[c0 + t * 16 + ln];
  float rq[2][4];
  #pragma unroll
  for (int r = 0; r < 2; ++r)
    #pragma unroll
    for (int g = 0; g < 4; ++g) rq[r][g] = rowsq[row0 + r * 16 + kb * 4 + g];

  #pragma unroll
  for (int r = 0; r < 2; ++r) {
    #pragma unroll
    for (int g = 0; g < 4; ++g) {
      float v = __builtin_inff();
      #pragma unroll
      for (int t = 0; t < 16; ++t) {
        float dd = (rq[r][g] + bvl[t]) - 2.0f * acc[r][t][g];
        v = fminf(v, dd);
      }
      #pragma unroll
      for (int m = 1; m < 16; m <<= 1) v = fminf(v, __shfl_xor(v, m));
      if (ln == 0) minb[rh2 * 32 + r * 16 + kb * 4 + g][cg] = v;
    }
  }
  __syncthreads();
  if (tid < 64) {
    rowminf[tid] = fminf(fminf(minb[tid][0], minb[tid][1]),
                         fminf(minb[tid][2], minb[tid][3]));
    cnt[tid] = 0;
  }
  __syncthreads();
  #pragma unroll
  for (int r = 0; r < 2; ++r) {
    #pragma unroll
    for (int g = 0; g < 4; ++g) {
      const int rowloc = rh2 * 32 + r * 16 + kb * 4 + g;
      const float thr = rowminf[rowloc] + MARGIN;
      #pragma unroll
      for (int t = 0; t < 16; ++t) {
        float dd = (rq[r][g] + bvl[t]) - 2.0f * acc[r][t][g];
        if (dd <= thr) {
          unsigned slot = atomicAdd(&cnt[rowloc], 1u);
          if (slot < CAP)
            survq[(size_t)(blockIdx.x * 64 + rowloc) * CAP + slot] =
                (unsigned)(c0 + t * 16 + ln);
        }
      }
    }
  }
  __syncthreads();
  if (tid < 64) counts[blockIdx.x * 64 + tid] = cnt[tid];
}

// ============ fused exact rescore + residual update (verified r14/r15) ============
__global__ __launch_bounds__(256) void k_exupd(const float* __restrict__ x,
                                               const float* __restrict__ cb,
                                               const float* __restrict__ bv,
                                               const float* __restrict__ rowsq,
                                               const unsigned* __restrict__ survq,
                                               const unsigned* __restrict__ counts,
                                               int* __restrict__ idxh,
                                               float* __restrict__ fidx,
                                               float* __restrict__ tq,
                                               float* __restrict__ part,
                                               float* __restrict__ rowsq_o,
                                               unsigned short* __restrict__ rhi,
                                               int lvl) {
  __shared__ __align__(16) float rlds[16][260];
  __shared__ int idsh[16];
  __shared__ float sred[256];
  __shared__ float rsum[16];

  const int tid = threadIdx.x;
  const int rr = tid >> 4;
  const int l16 = tid & 15;
  const int row = blockIdx.x * 16 + rr;
  const size_t obase = (size_t)row * DIM + l16 * 16;
  const float* cb_l = cb + (size_t)lvl * KCODES * DIM;
  const float* bv_l = bv + lvl * KCODES;

  // ---- phase A: residual via verified fl chain; stage row in LDS ----
  float4 xj[4], rj[4];
  {
    const float4* xp = reinterpret_cast<const float4*>(x + obase);
    #pragma unroll
    for (int j = 0; j < 4; ++j) { xj[j] = xp[j]; rj[j] = xj[j]; }
    for (int p = 0; p < lvl; ++p) {
      const float4* qp = reinterpret_cast<const float4*>(
          cb + ((size_t)p * KCODES + idxh[p * NROWS + row]) * DIM + l16 * 16);
      #pragma unroll
      for (int j = 0; j < 4; ++j) {
        float4 q = qp[j];
        rj[j].x -= q.x; rj[j].y -= q.y; rj[j].z -= q.z; rj[j].w -= q.w;
      }
    }
    #pragma unroll
    for (int j = 0; j < 4; ++j)
      *reinterpret_cast<float4*>(&rlds[rr][l16 * 16 + 4 * j]) = rj[j];
  }
  __syncthreads();

  // ---- phase B: exact chains on survivors ----
  const float A = rowsq[row];
  const unsigned n = counts[row];
  unsigned long long best = ~0ull;

#define CHAIN(CODE)                                                            \
  {                                                                            \
    const float* cp2 = cb_l + (size_t)(CODE) * DIM;                            \
    float a0 = 0.f;                                                            \
    _Pragma("unroll 8")                                                        \
    for (int dv = 0; dv < DIM / 4; ++dv) {                                     \
      float4 rv = *reinterpret_cast<const float4*>(&rlds[rr][dv * 4]);         \
      float4 cv = *reinterpret_cast<const float4*>(cp2 + dv * 4);              \
      a0 = fmaf(rv.x, cv.x, a0); a0 = fmaf(rv.y, cv.y, a0);                    \
      a0 = fmaf(rv.z, cv.z, a0); a0 = fmaf(rv.w, cv.w, a0);                    \
    }                                                                          \
    float t = A + bv_l[(CODE)];   /* fl(A + B) */                              \
    float dd = t - 2.0f * a0;     /* one rounding (2*dot exact) */             \
    unsigned long long pk =                                                    \
        ((unsigned long long)__float_as_uint(dd) << 32) | (unsigned)(CODE);    \
    best = (pk < best) ? pk : best;                                            \
  }

  if (n <= CAP) {
    for (unsigned s = l16; s < n; s += 16) {
      unsigned code = survq[(size_t)row * CAP + s];
      CHAIN(code);
    }
  } else {
    for (unsigned c = l16; c < KCODES; c += 16) CHAIN(c);  // safety net
  }
#undef CHAIN

  #pragma unroll
  for (int m = 1; m < 16; m <<= 1) {
    unsigned long long o = __shfl_xor(best, m);
    best = (o < best) ? o : best;
  }
  if (l16 == 0) {
    const int id = (int)(best & 0xffffffffull);
    idxh[lvl * NROWS + row] = id;
    fidx[lvl * NROWS + row] = (float)id;
    idsh[rr] = id;
  }
  __syncthreads();

  // ---- phase C: verified k_update math inline ----
  const int id = idsh[rr];
  const float4* cpc = reinterpret_cast<const float4*>(
      cb_l + (size_t)id * DIM + l16 * 16);
  float4* tp = reinterpret_cast<float4*>(tq + obase);
  float nn[16];
  float e = 0.f;
  #pragma unroll
  for (int j = 0; j < 4; ++j) {
    float4 c = cpc[j];
    float n0 = rj[j].x - c.x, n1 = rj[j].y - c.y;
    float n2 = rj[j].z - c.z, n3 = rj[j].w - c.w;
    nn[4 * j + 0] = n0; nn[4 * j + 1] = n1; nn[4 * j + 2] = n2; nn[4 * j + 3] = n3;
    e += (n0 * n0 + n1 * n1) + (n2 * n2 + n3 * n3);
    float4 tv;
    if (lvl == 0) {
      tv = c;
    } else {
      tv = tp[j];
      tv.x += c.x; tv.y += c.y; tv.z += c.z; tv.w += c.w;
    }
    if (lvl == 3) {
      tv.x = xj[j].x + (tv.x - xj[j].x); tv.y = xj[j].y + (tv.y - xj[j].y);
      tv.z = xj[j].z + (tv.z - xj[j].z); tv.w = xj[j].w + (tv.w - xj[j].w);
    }
    tp[j] = tv;
  }

  if (lvl < 3) {
    unsigned w[8];
    #pragma unroll
    for (int k = 0; k < 8; ++k)
      w[k] = (unsigned)f2bf(nn[2 * k]) | ((unsigned)f2bf(nn[2 * k + 1]) << 16);
    unsigned short* base = rhi + (size_t)blockIdx.x * 4096;
    const int ks = l16 >> 1;
    const int kb0 = (l16 & 1) * 2;
    *reinterpret_cast<uint4*>(base + ks * 512 + kb0 * 128 + rr * 8) =
        make_uint4(w[0], w[1], w[2], w[3]);
    *reinterpret_cast<uint4*>(base + ks * 512 + (kb0 + 1) * 128 + rr * 8) =
        make_uint4(w[4], w[5], w[6], w[7]);
  }

  sred[tid] = e;
  __syncthreads();
  if (tid < 16) {
    float s = 0.f;
    #pragma unroll
    for (int k = 0; k < 16; ++k) s += sred[tid * 16 + k];
    rsum[tid] = s;
    if (lvl < 3) rowsq_o[blockIdx.x * 16 + tid] = s;
  }
  __syncthreads();
  if (tid == 0) {
    float p = 0.f;
    #pragma unroll
    for (int k = 0; k < 16; ++k) p += rsum[k];
    part[blockIdx.x] = p;
  }
}

// ============ loss finalize (unchanged) ============
__global__ __launch_bounds__(256) void k_loss(const float* __restrict__ part,
                                              float* __restrict__ out) {
  __shared__ float s[256];
  const int tid = threadIdx.x;
  float means[4];
  for (int l = 0; l < 4; ++l) {
    float sum = 0.f;
    for (int i = tid; i < 2048; i += 256) sum += part[l * 2048 + i];
    s[tid] = sum;
    __syncthreads();
    for (int st = 128; st > 0; st >>= 1) {
      if (tid < st) s[tid] += s[tid + st];
      __syncthreads();
    }
    means[l] = s[0] * (1.0f / 8388608.0f);
    __syncthreads();
  }
  if (tid == 0) {
    float t = ((means[0] + means[1]) + means[2]) + means[3];
    float loss = t * 0.25f;
    out[0] = loss;
    out[1] = loss;
  }
}

extern "C" void kernel_launch(void* const* d_in, const int* in_sizes, int n_in,
                              void* d_out, int out_size, void* d_ws, size_t ws_size,
                              hipStream_t stream) {
  const float* x  = (const float*)d_in[0];
  const float* cb = (const float*)d_in[1];
  float* out = (float*)d_out;
  float* ws  = (float*)d_ws;

  // ws layout (float units)
  unsigned short* rhi = (unsigned short*)ws;                         // 4194304 f
  unsigned short* chi = (unsigned short*)(ws + 4194304);             // 524288 f
  unsigned* survq  = (unsigned*)(ws + 4194304 + 524288);             // 2097152 f
  unsigned* counts = (unsigned*)(ws + 4194304 + 524288 + 2097152);   // 32768 f
  int* idxh        = (int*)(ws + 4194304 + 524288 + 2097152 + 32768);  // 131072 f
  float* bv    = ws + 4194304 + 524288 + 2097152 + 32768 + 131072;   // 4096
  float* rowsq = bv + 4096;                                          // 32768
  float* part  = rowsq + 32768;                                      // 8192

  float* tq      = out;                    // total_quant accumulates in d_out
  float* lossout = out + 8388608;
  float* fidx    = out + 8388610;

  k_bnorm<<<16, 256, 0, stream>>>(cb, bv);
  k_csplit<<<256, 256, 0, stream>>>(cb, chi);
  k_prep<<<2048, 256, 0, stream>>>(x, rhi, rowsq);

  for (int l = 0; l < NLEV; ++l) {
    k_screen<<<512, 512, 0, stream>>>(rhi, chi + (size_t)l * KCODES * DIM,
                                      bv + l * KCODES, rowsq, survq, counts);
    k_exupd<<<2048, 256, 0, stream>>>(x, cb, bv, rowsq, survq, counts,
                                      idxh, fidx, tq, part + l * 2048,
                                      rowsq, rhi, l);
  }

  k_loss<<<1, 256, 0, stream>>>(part, lossout);
}